// Round 2
// baseline (492.003 us; speedup 1.0000x reference)
//
#include <hip/hip_runtime.h>

#define DIM 32

typedef float v2f __attribute__((ext_vector_type(2)));

#if __has_builtin(__builtin_amdgcn_global_atomic_fadd_v2f32)
#define HAVE_PK_FADD 1
#endif

__global__ void deg_kernel(const int* __restrict__ dst, int* __restrict__ deg, int E) {
    int e = blockIdx.x * blockDim.x + threadIdx.x;
    if (e < E) atomicAdd(&deg[dst[e]], 1);
}

__global__ void dis_kernel(const int* __restrict__ deg, float* __restrict__ dis, int n) {
    int i = blockIdx.x * blockDim.x + threadIdx.x;
    if (i < n) dis[i] = rsqrtf((float)deg[i] + 1.0f);  // +1 self-loop; always > 0
}

// hs[row] = (x @ W)[row] * dis[row]
__global__ void gemm_kernel(const float* __restrict__ x, const float* __restrict__ W,
                            const float* __restrict__ dis, float* __restrict__ hs, int n) {
    __shared__ float Ws[DIM * DIM];
    int tid = threadIdx.x;
    for (int i = tid; i < DIM * DIM; i += blockDim.x) Ws[i] = W[i];
    __syncthreads();
    int row = blockIdx.x * (blockDim.x / DIM) + (tid >> 5);
    int col = tid & 31;
    if (row < n) {
        const float* xr = x + row * DIM;
        float s = 0.f;
#pragma unroll
        for (int k = 0; k < DIM; ++k) s += xr[k] * Ws[k * DIM + col];
        hs[row * DIM + col] = s * dis[row];
    }
}

// accum[d] += hs[s]  (16 lanes per edge, float2 per lane, packed atomics)
__global__ void scatter_kernel(const int* __restrict__ src, const int* __restrict__ dst,
                               const float* __restrict__ hs,
                               float* __restrict__ accum, int E) {
    int t = blockIdx.x * blockDim.x + threadIdx.x;
    int e = t >> 4;
    int f = t & 15;  // float2 index: features [2f, 2f+1]
    if (e < E) {
        int s = src[e], d = dst[e];
        const float2* hs2 = (const float2*)hs;
        float2 val = hs2[s * (DIM / 2) + f];
#ifdef HAVE_PK_FADD
        v2f* p = (v2f*)(accum + (size_t)d * DIM + 2 * f);
        v2f v; v.x = val.x; v.y = val.y;
        __builtin_amdgcn_global_atomic_fadd_v2f32(p, v);
#else
        atomicAdd(&accum[(size_t)d * DIM + 2 * f], val.x);
        atomicAdd(&accum[(size_t)d * DIM + 2 * f + 1], val.y);
#endif
    }
}

__global__ void final_kernel(const float* __restrict__ accum, const float* __restrict__ hs,
                             const float* __restrict__ dis, const float* __restrict__ b,
                             float* __restrict__ out, int n) {
    int t = blockIdx.x * blockDim.x + threadIdx.x;
    int i = t >> 5;
    int f = t & 31;
    if (i >= n) return;
    float v = dis[i] * (accum[i * DIM + f] + hs[i * DIM + f]) + b[f];
    float s1 = v, s2 = v * v;
#pragma unroll
    for (int off = 16; off > 0; off >>= 1) {
        s1 += __shfl_xor(s1, off, 32);
        s2 += __shfl_xor(s2, off, 32);
    }
    float mean = s1 * (1.0f / 32.0f);
    float var = s2 * (1.0f / 32.0f) - mean * mean;
    var = fmaxf(var, 0.0f);
    float o = (v - mean) * rsqrtf(var + 1e-6f);
    out[i * DIM + f] = (o >= 0.f) ? o : 0.01f * o;
}

extern "C" void kernel_launch(void* const* d_in, const int* in_sizes, int n_in,
                              void* d_out, int out_size, void* d_ws, size_t ws_size,
                              hipStream_t stream) {
    const float* x = (const float*)d_in[0];
    const int* edge_index = (const int*)d_in[1];
    const float* W = (const float*)d_in[2];
    const float* b = (const float*)d_in[3];
    float* out = (float*)d_out;

    const int N = in_sizes[0] / DIM;      // 100000
    const int E = in_sizes[1] / 2;        // 1600000
    const int* src = edge_index;          // edge_index[0, :]
    const int* dst = edge_index + E;      // edge_index[1, :]

    float* accum = (float*)d_ws;              // N*DIM
    float* hs    = accum + (size_t)N * DIM;   // N*DIM
    int*   deg   = (int*)(hs + (size_t)N * DIM);  // N
    float* dis   = (float*)(deg + N);         // N

    hipMemsetAsync(accum, 0, (size_t)N * DIM * sizeof(float), stream);
    hipMemsetAsync(deg, 0, (size_t)N * sizeof(int), stream);

    deg_kernel<<<(E + 255) / 256, 256, 0, stream>>>(dst, deg, E);
    dis_kernel<<<(N + 255) / 256, 256, 0, stream>>>(deg, dis, N);
    gemm_kernel<<<(N + 7) / 8, 256, 0, stream>>>(x, W, dis, hs, N);
    scatter_kernel<<<(E * 16 + 255) / 256, 256, 0, stream>>>(src, dst, hs, accum, E);
    final_kernel<<<(N + 7) / 8, 256, 0, stream>>>(accum, hs, dis, b, out, N);
}

// Round 3
// 326.393 us; speedup vs baseline: 1.5074x; 1.5074x over previous
//
#include <hip/hip_runtime.h>

#define DIM 32
#define SCAN_B 256

__global__ void deg_kernel(const int* __restrict__ dst, int* __restrict__ deg, int E) {
    int e = blockIdx.x * blockDim.x + threadIdx.x;
    if (e < E) atomicAdd(&deg[dst[e]], 1);
}

// per-block sums of deg
__global__ void partial_kernel(const int* __restrict__ deg, int* __restrict__ partials, int n) {
    __shared__ int s[SCAN_B];
    int t = threadIdx.x;
    int i = blockIdx.x * SCAN_B + t;
    s[t] = (i < n) ? deg[i] : 0;
    __syncthreads();
    for (int off = SCAN_B / 2; off > 0; off >>= 1) {
        if (t < off) s[t] += s[t + off];
        __syncthreads();
    }
    if (t == 0) partials[blockIdx.x] = s[0];
}

// exclusive scan of block partials (single block, nb <= 512)
__global__ void scan_partials_kernel(int* __restrict__ partials, int nb) {
    __shared__ int s[512];
    int t = threadIdx.x;
    int v = (t < nb) ? partials[t] : 0;
    s[t] = v;
    __syncthreads();
    for (int off = 1; off < 512; off <<= 1) {
        int x = (t >= off) ? s[t - off] : 0;
        __syncthreads();
        s[t] += x;
        __syncthreads();
    }
    if (t < nb) partials[t] = s[t] - v;  // exclusive
}

// per-element exclusive scan -> rowptr, cursor; fused dis = rsqrt(deg+1)
__global__ void scan_kernel(const int* __restrict__ deg, const int* __restrict__ partials,
                            int* __restrict__ rowptr, int* __restrict__ cursor,
                            float* __restrict__ dis, int n) {
    __shared__ int s[SCAN_B];
    int t = threadIdx.x;
    int i = blockIdx.x * SCAN_B + t;
    int v = (i < n) ? deg[i] : 0;
    s[t] = v;
    __syncthreads();
    for (int off = 1; off < SCAN_B; off <<= 1) {
        int x = (t >= off) ? s[t - off] : 0;
        __syncthreads();
        s[t] += x;
        __syncthreads();
    }
    if (i < n) {
        int excl = s[t] - v + partials[blockIdx.x];
        rowptr[i] = excl;
        cursor[i] = excl;
        dis[i] = rsqrtf((float)v + 1.0f);
        if (i == n - 1) rowptr[n] = excl + v;
    }
}

// edge_sorted[pos] = src, bucketed by dst
__global__ void fill_kernel(const int* __restrict__ src, const int* __restrict__ dst,
                            int* __restrict__ cursor, int* __restrict__ edge_sorted, int E) {
    int e = blockIdx.x * blockDim.x + threadIdx.x;
    if (e < E) {
        int d = dst[e];
        int pos = atomicAdd(&cursor[d], 1);
        edge_sorted[pos] = src[e];
    }
}

// hs[row] = (x @ W)[row] * dis[row]
__global__ void gemm_kernel(const float* __restrict__ x, const float* __restrict__ W,
                            const float* __restrict__ dis, float* __restrict__ hs, int n) {
    __shared__ float Ws[DIM * DIM];
    int tid = threadIdx.x;
    for (int i = tid; i < DIM * DIM; i += blockDim.x) Ws[i] = W[i];
    __syncthreads();
    int row = blockIdx.x * (blockDim.x / DIM) + (tid >> 5);
    int col = tid & 31;
    if (row < n) {
        const float* xr = x + row * DIM;
        float s = 0.f;
#pragma unroll
        for (int k = 0; k < DIM; ++k) s += xr[k] * Ws[k * DIM + col];
        hs[row * DIM + col] = s * dis[row];
    }
}

// per dst node: sum hs[src] over CSR row, fused epilogue (norm + leakyrelu)
__global__ void gather_kernel(const int* __restrict__ rowptr, const int* __restrict__ edge_sorted,
                              const float* __restrict__ hs, const float* __restrict__ dis,
                              const float* __restrict__ b, float* __restrict__ out, int n) {
    int t = blockIdx.x * blockDim.x + threadIdx.x;
    int i = t >> 5;
    int f = t & 31;
    if (i >= n) return;
    int beg = rowptr[i], end = rowptr[i + 1];
    float acc = 0.f;
    int j = beg;
    for (; j + 4 <= end; j += 4) {
        int s0 = edge_sorted[j];
        int s1 = edge_sorted[j + 1];
        int s2 = edge_sorted[j + 2];
        int s3 = edge_sorted[j + 3];
        float a0 = hs[s0 * DIM + f];
        float a1 = hs[s1 * DIM + f];
        float a2 = hs[s2 * DIM + f];
        float a3 = hs[s3 * DIM + f];
        acc += a0 + a1 + a2 + a3;
    }
    for (; j < end; ++j) acc += hs[edge_sorted[j] * DIM + f];

    float v = dis[i] * (acc + hs[i * DIM + f]) + b[f];
    float s1v = v, s2v = v * v;
#pragma unroll
    for (int off = 16; off > 0; off >>= 1) {
        s1v += __shfl_xor(s1v, off, 32);
        s2v += __shfl_xor(s2v, off, 32);
    }
    float mean = s1v * (1.0f / 32.0f);
    float var = s2v * (1.0f / 32.0f) - mean * mean;
    var = fmaxf(var, 0.0f);
    float o = (v - mean) * rsqrtf(var + 1e-6f);
    out[i * DIM + f] = (o >= 0.f) ? o : 0.01f * o;
}

extern "C" void kernel_launch(void* const* d_in, const int* in_sizes, int n_in,
                              void* d_out, int out_size, void* d_ws, size_t ws_size,
                              hipStream_t stream) {
    const float* x = (const float*)d_in[0];
    const int* edge_index = (const int*)d_in[1];
    const float* W = (const float*)d_in[2];
    const float* b = (const float*)d_in[3];
    float* out = (float*)d_out;

    const int N = in_sizes[0] / DIM;      // 100000
    const int E = in_sizes[1] / 2;        // 1600000
    const int* src = edge_index;
    const int* dst = edge_index + E;

    const int NBLK = (N + SCAN_B - 1) / SCAN_B;  // 391 (<=512 required)

    char* w = (char*)d_ws;
    float* hs          = (float*)w;                 w += (size_t)N * DIM * sizeof(float);
    int*   edge_sorted = (int*)w;                   w += (size_t)E * sizeof(int);
    int*   deg         = (int*)w;                   w += (size_t)N * sizeof(int);
    int*   cursor      = (int*)w;                   w += (size_t)N * sizeof(int);
    int*   rowptr      = (int*)w;                   w += (size_t)(N + 1) * sizeof(int);
    float* dis         = (float*)w;                 w += (size_t)N * sizeof(float);
    int*   partials    = (int*)w;                   w += 1024 * sizeof(int);

    hipMemsetAsync(deg, 0, (size_t)N * sizeof(int), stream);

    deg_kernel<<<(E + 255) / 256, 256, 0, stream>>>(dst, deg, E);
    partial_kernel<<<NBLK, SCAN_B, 0, stream>>>(deg, partials, N);
    scan_partials_kernel<<<1, 512, 0, stream>>>(partials, NBLK);
    scan_kernel<<<NBLK, SCAN_B, 0, stream>>>(deg, partials, rowptr, cursor, dis, N);
    fill_kernel<<<(E + 255) / 256, 256, 0, stream>>>(src, dst, cursor, edge_sorted, E);
    gemm_kernel<<<(N + 7) / 8, 256, 0, stream>>>(x, W, dis, hs, N);
    gather_kernel<<<(N * 32 + 255) / 256, 256, 0, stream>>>(rowptr, edge_sorted, hs, dis, b, out, N);
}

// Round 4
// 280.254 us; speedup vs baseline: 1.7556x; 1.1646x over previous
//
#include <hip/hip_runtime.h>

#define DIM 32
#define SCAN_B 256
#define NSLICE 8

__global__ void zero_kernel(int* __restrict__ p, int n) {
    int i = blockIdx.x * blockDim.x + threadIdx.x;
    if (i < n) p[i] = 0;
}

__global__ void deg_kernel(const int* __restrict__ dst, int* __restrict__ deg, int E) {
    int e = blockIdx.x * blockDim.x + threadIdx.x;
    if (e < E) atomicAdd(&deg[dst[e]], 1);
}

// per-block sums of deg
__global__ void partial_kernel(const int* __restrict__ deg, int* __restrict__ partials, int n) {
    __shared__ int s[SCAN_B];
    int t = threadIdx.x;
    int i = blockIdx.x * SCAN_B + t;
    s[t] = (i < n) ? deg[i] : 0;
    __syncthreads();
    for (int off = SCAN_B / 2; off > 0; off >>= 1) {
        if (t < off) s[t] += s[t + off];
        __syncthreads();
    }
    if (t == 0) partials[blockIdx.x] = s[0];
}

// exclusive scan of block partials (single block, nb <= 512)
__global__ void scan_partials_kernel(int* __restrict__ partials, int nb) {
    __shared__ int s[512];
    int t = threadIdx.x;
    int v = (t < nb) ? partials[t] : 0;
    s[t] = v;
    __syncthreads();
    for (int off = 1; off < 512; off <<= 1) {
        int x = (t >= off) ? s[t - off] : 0;
        __syncthreads();
        s[t] += x;
        __syncthreads();
    }
    if (t < nb) partials[t] = s[t] - v;  // exclusive
}

// per-element exclusive scan -> rowptr, cursor; fused dis = rsqrt(deg+1)
__global__ void scan_kernel(const int* __restrict__ deg, const int* __restrict__ partials,
                            int* __restrict__ rowptr, int* __restrict__ cursor,
                            float* __restrict__ dis, int n) {
    __shared__ int s[SCAN_B];
    int t = threadIdx.x;
    int i = blockIdx.x * SCAN_B + t;
    int v = (i < n) ? deg[i] : 0;
    s[t] = v;
    __syncthreads();
    for (int off = 1; off < SCAN_B; off <<= 1) {
        int x = (t >= off) ? s[t - off] : 0;
        __syncthreads();
        s[t] += x;
        __syncthreads();
    }
    if (i < n) {
        int excl = s[t] - v + partials[blockIdx.x];
        rowptr[i] = excl;
        cursor[i] = excl;
        dis[i] = rsqrtf((float)v + 1.0f);
        if (i == n - 1) rowptr[n] = excl + v;
    }
}

// XCD-sliced fill: slice = blockIdx & 7 (consecutive blocks round-robin XCDs,
// so all writers of one dst-slice share one XCD's L2 -> lines fill before
// eviction -> write amp ~1). Each block scans all edges, keeps its slice.
__global__ void fill_sliced_kernel(const int* __restrict__ src, const int* __restrict__ dst,
                                   int* __restrict__ cursor, int* __restrict__ edge_sorted,
                                   int E, int sliceN) {
    int slice = blockIdx.x & (NSLICE - 1);
    int blockInSlice = blockIdx.x >> 3;
    int blocksPerSlice = gridDim.x >> 3;
    int lo = slice * sliceN;
    int hi = lo + sliceN;  // dst < N always, last slice padded is fine
    int stride = blocksPerSlice * blockDim.x;
    for (int e = blockInSlice * blockDim.x + threadIdx.x; e < E; e += stride) {
        int d = dst[e];
        int s = src[e];
        if (d >= lo && d < hi) {
            int pos = atomicAdd(&cursor[d], 1);
            edge_sorted[pos] = s;
        }
    }
}

// hs[row] = (x @ W)[row] * dis[row]
__global__ void gemm_kernel(const float* __restrict__ x, const float* __restrict__ W,
                            const float* __restrict__ dis, float* __restrict__ hs, int n) {
    __shared__ float Ws[DIM * DIM];
    int tid = threadIdx.x;
    for (int i = tid; i < DIM * DIM; i += blockDim.x) Ws[i] = W[i];
    __syncthreads();
    int row = blockIdx.x * (blockDim.x / DIM) + (tid >> 5);
    int col = tid & 31;
    if (row < n) {
        const float* xr = x + row * DIM;
        float s = 0.f;
#pragma unroll
        for (int k = 0; k < DIM; ++k) s += xr[k] * Ws[k * DIM + col];
        hs[row * DIM + col] = s * dis[row];
    }
}

// per dst node: sum hs[src] over CSR row, fused epilogue (norm + leakyrelu)
__global__ void gather_kernel(const int* __restrict__ rowptr, const int* __restrict__ edge_sorted,
                              const float* __restrict__ hs, const float* __restrict__ dis,
                              const float* __restrict__ b, float* __restrict__ out, int n) {
    int t = blockIdx.x * blockDim.x + threadIdx.x;
    int i = t >> 5;
    int f = t & 31;
    if (i >= n) return;
    int beg = rowptr[i], end = rowptr[i + 1];
    float acc = 0.f;
    int j = beg;
    for (; j + 4 <= end; j += 4) {
        int s0 = edge_sorted[j];
        int s1 = edge_sorted[j + 1];
        int s2 = edge_sorted[j + 2];
        int s3 = edge_sorted[j + 3];
        float a0 = hs[s0 * DIM + f];
        float a1 = hs[s1 * DIM + f];
        float a2 = hs[s2 * DIM + f];
        float a3 = hs[s3 * DIM + f];
        acc += a0 + a1 + a2 + a3;
    }
    for (; j < end; ++j) acc += hs[edge_sorted[j] * DIM + f];

    float v = dis[i] * (acc + hs[i * DIM + f]) + b[f];
    float s1v = v, s2v = v * v;
#pragma unroll
    for (int off = 16; off > 0; off >>= 1) {
        s1v += __shfl_xor(s1v, off, 32);
        s2v += __shfl_xor(s2v, off, 32);
    }
    float mean = s1v * (1.0f / 32.0f);
    float var = s2v * (1.0f / 32.0f) - mean * mean;
    var = fmaxf(var, 0.0f);
    float o = (v - mean) * rsqrtf(var + 1e-6f);
    out[i * DIM + f] = (o >= 0.f) ? o : 0.01f * o;
}

extern "C" void kernel_launch(void* const* d_in, const int* in_sizes, int n_in,
                              void* d_out, int out_size, void* d_ws, size_t ws_size,
                              hipStream_t stream) {
    const float* x = (const float*)d_in[0];
    const int* edge_index = (const int*)d_in[1];
    const float* W = (const float*)d_in[2];
    const float* b = (const float*)d_in[3];
    float* out = (float*)d_out;

    const int N = in_sizes[0] / DIM;      // 100000
    const int E = in_sizes[1] / 2;        // 1600000
    const int* src = edge_index;
    const int* dst = edge_index + E;

    const int NBLK = (N + SCAN_B - 1) / SCAN_B;  // 391 (<=512 required)
    const int sliceN = (N + NSLICE - 1) / NSLICE;

    char* w = (char*)d_ws;
    float* hs          = (float*)w;                 w += (size_t)N * DIM * sizeof(float);
    int*   edge_sorted = (int*)w;                   w += (size_t)E * sizeof(int);
    int*   deg         = (int*)w;                   w += (size_t)N * sizeof(int);
    int*   cursor      = (int*)w;                   w += (size_t)N * sizeof(int);
    int*   rowptr      = (int*)w;                   w += (size_t)(N + 1) * sizeof(int);
    float* dis         = (float*)w;                 w += (size_t)N * sizeof(float);
    int*   partials    = (int*)w;                   w += 1024 * sizeof(int);

    zero_kernel<<<(N + 255) / 256, 256, 0, stream>>>(deg, N);
    deg_kernel<<<(E + 255) / 256, 256, 0, stream>>>(dst, deg, E);
    partial_kernel<<<NBLK, SCAN_B, 0, stream>>>(deg, partials, N);
    scan_partials_kernel<<<1, 512, 0, stream>>>(partials, NBLK);
    scan_kernel<<<NBLK, SCAN_B, 0, stream>>>(deg, partials, rowptr, cursor, dis, N);
    // 8 slices x 104 blocks = 832 blocks (~3.25/CU)
    fill_sliced_kernel<<<NSLICE * 104, 256, 0, stream>>>(src, dst, cursor, edge_sorted, E, sliceN);
    gemm_kernel<<<(N + 7) / 8, 256, 0, stream>>>(x, W, dis, hs, N);
    gather_kernel<<<(N * 32 + 255) / 256, 256, 0, stream>>>(rowptr, edge_sorted, hs, dis, b, out, N);
}